// Round 1
// baseline (658.391 us; speedup 1.0000x reference)
//
#include <hip/hip_runtime.h>
#include <hip/hip_bf16.h>

typedef __attribute__((ext_vector_type(8))) short short8;
typedef __attribute__((ext_vector_type(4))) float floatx4;

static __device__ __forceinline__ unsigned short f2bf(float f){
  union { float f; unsigned int u; } v; v.f = f;
  return (unsigned short)((v.u + 0x7FFFu + ((v.u >> 16) & 1u)) >> 16);  // RNE
}

// Stage a ROWS x 128 fp32 tile -> bf16 LDS tile, XOR-swizzled (byte ^= (row&7)<<4).
// ldsbase: tile base in LDS; src points at (row0, col0); ld = row stride in elements.
template<int ROWS>
static __device__ __forceinline__ void stage_tile(char* ldsbase, const float* __restrict__ src,
                                                  int ld, int tid){
  #pragma unroll
  for (int w = 0; w < ROWS/32; ++w){            // ROWS*16 groups of 8 elems / 512 threads
    int g = w*512 + tid;
    int row = g >> 4, k8 = g & 15;
    const float* p = src + (size_t)row*ld + k8*8;
    floatx4 v0 = *(const floatx4*)p;
    floatx4 v1 = *(const floatx4*)(p+4);
    short8 s;
    s[0] = (short)f2bf(v0[0]); s[1] = (short)f2bf(v0[1]);
    s[2] = (short)f2bf(v0[2]); s[3] = (short)f2bf(v0[3]);
    s[4] = (short)f2bf(v1[0]); s[5] = (short)f2bf(v1[1]);
    s[6] = (short)f2bf(v1[2]); s[7] = (short)f2bf(v1[3]);
    *(short8*)(ldsbase + row*256 + ((k8*16) ^ ((row & 7) << 4))) = s;
  }
}

static __device__ __forceinline__ short8 frag_ld(const char* ldsbase, int row, int kbyte){
  return *(const short8*)(ldsbase + row*256 + (kbyte ^ ((row & 7) << 4)));
}

// MODE 0: out = relu(A@B^T + bias)   (x kernel)
// MODE 1: out = A@B^T                (b2 bias-GEMV init of r_ol)
// MODE 2: out = A@B^T + bias         (logits)
// A: [1024][512] fp32, staged/cvt to bf16. B: [*][512] fp32 rows. K = 512.
template<int MODE>
__global__ __launch_bounds__(512)
void gemm_plain(const float* __restrict__ Asrc, const float* __restrict__ Bsrc,
                const float* __restrict__ bias, float* __restrict__ out, int out_ld){
  __shared__ char smem[98304];
  char* At = smem;            // [256][128] bf16 swz
  char* Bt = smem + 65536;    // [128][128] bf16 swz
  const int tid  = threadIdx.x;
  const int lane = tid & 63, w = tid >> 6;
  const int wm = w & 3, wn = w >> 2;
  const int bid = blockIdx.x;
  const int t0 = (bid & 3) * 256;
  const int c0 = (bid >> 2) * 128;
  const int rbase = wm*64, cbase = wn*64;

  floatx4 acc[4][4];
  #pragma unroll
  for (int i=0;i<4;++i)
    #pragma unroll
    for (int j=0;j<4;++j) acc[i][j] = floatx4{0.f,0.f,0.f,0.f};

  for (int kb = 0; kb < 4; ++kb){
    __syncthreads();
    stage_tile<256>(At, Asrc + (size_t)t0*512 + kb*128, 512, tid);
    stage_tile<128>(Bt, Bsrc + (size_t)c0*512 + kb*128, 512, tid);
    __syncthreads();
    #pragma unroll
    for (int ks = 0; ks < 4; ++ks){
      const int kbyte = (ks*32 + (lane>>4)*8) * 2;
      short8 af[4], bf[4];
      #pragma unroll
      for (int mi=0; mi<4; ++mi) af[mi] = frag_ld(At, rbase + mi*16 + (lane&15), kbyte);
      #pragma unroll
      for (int ni=0; ni<4; ++ni) bf[ni] = frag_ld(Bt, cbase + ni*16 + (lane&15), kbyte);
      #pragma unroll
      for (int mi=0; mi<4; ++mi)
        #pragma unroll
        for (int ni=0; ni<4; ++ni)
          acc[mi][ni] = __builtin_amdgcn_mfma_f32_16x16x32_bf16(af[mi], bf[ni], acc[mi][ni], 0,0,0);
    }
  }
  #pragma unroll
  for (int mi=0; mi<4; ++mi){
    #pragma unroll
    for (int ni=0; ni<4; ++ni){
      #pragma unroll
      for (int rg=0; rg<4; ++rg){
        int t = t0 + rbase + mi*16 + (lane>>4)*4 + rg;
        int c = c0 + cbase + ni*16 + (lane&15);
        float v = acc[mi][ni][rg];
        if (MODE == 0) { v += bias[c]; v = v > 0.f ? v : 0.f; }
        if (MODE == 2) { v += bias[c]; }
        out[(size_t)t*out_ld + c] = v;
      }
    }
  }
}

// Fused per-n GEMM: r_ol[t,h] += sum_n r[t,n] * sum_k x_bf[t,k] * W2_bf[h*512+n, k]
// Grid: 512 = 4 token-tiles x 4 h-tiles x 32 n-splits (16 n each).
__global__ __launch_bounds__(512)
void k2_fused(const float* __restrict__ x, const float* __restrict__ r,
              const float* __restrict__ W2, float* __restrict__ r_ol){
  __shared__ char smem[115712];
  char* At  = smem;                      // x tile [256][128] bf16 swz
  char* Bt  = smem + 65536;              // W2 tile [128][128] bf16 swz
  float* RT = (float*)(smem + 98304);    // r tile [256][17] fp32 (padded)
  const int tid  = threadIdx.x;
  const int lane = tid & 63, w = tid >> 6;
  const int wm = w & 3, wn = w >> 2;
  const int bid = blockIdx.x;
  const int t0 = (bid & 3) * 256;
  const int h0 = ((bid >> 2) & 3) * 128;
  const int n0 = (bid >> 4) * 16;
  const int rbase = wm*64, cbase = wn*64;

  // stage r slice [256 rows][16 n] once
  #pragma unroll
  for (int i = 0; i < 8; ++i){
    int e = i*512 + tid;
    int row = e >> 4, c = e & 15;
    RT[row*17 + c] = r[(size_t)(t0+row)*512 + n0 + c];
  }

  floatx4 acc[4][4];
  #pragma unroll
  for (int i=0;i<4;++i)
    #pragma unroll
    for (int j=0;j<4;++j) acc[i][j] = floatx4{0.f,0.f,0.f,0.f};
  const floatx4 zero4 = {0.f,0.f,0.f,0.f};

  for (int kb = 0; kb < 4; ++kb){
    __syncthreads();                       // prior readers of At done
    stage_tile<256>(At, x + (size_t)t0*512 + kb*128, 512, tid);
    for (int n = 0; n < 16; ++n){
      __syncthreads();                     // prior readers of Bt done; At writes visible after next bar
      stage_tile<128>(Bt, W2 + (size_t)h0*262144 + (size_t)(n0+n)*512 + kb*128, 262144, tid);
      __syncthreads();                     // Bt (and At) visible
      floatx4 ct[4][4];
      #pragma unroll
      for (int ks = 0; ks < 4; ++ks){
        const int kbyte = (ks*32 + (lane>>4)*8) * 2;
        short8 af[4], bf[4];
        #pragma unroll
        for (int mi=0; mi<4; ++mi) af[mi] = frag_ld(At, rbase + mi*16 + (lane&15), kbyte);
        #pragma unroll
        for (int ni=0; ni<4; ++ni) bf[ni] = frag_ld(Bt, cbase + ni*16 + (lane&15), kbyte);
        #pragma unroll
        for (int mi=0; mi<4; ++mi)
          #pragma unroll
          for (int ni=0; ni<4; ++ni)
            ct[mi][ni] = __builtin_amdgcn_mfma_f32_16x16x32_bf16(
                af[mi], bf[ni], (ks==0) ? zero4 : ct[mi][ni], 0,0,0);
      }
      // fold: acc += r[t, n0+n] * ct   (fp32, on MFMA output fragments)
      #pragma unroll
      for (int mi=0; mi<4; ++mi){
        const int rrow = rbase + mi*16 + (lane>>4)*4;
        float rv0 = RT[(rrow+0)*17 + n];
        float rv1 = RT[(rrow+1)*17 + n];
        float rv2 = RT[(rrow+2)*17 + n];
        float rv3 = RT[(rrow+3)*17 + n];
        #pragma unroll
        for (int ni=0; ni<4; ++ni){
          acc[mi][ni][0] += rv0 * ct[mi][ni][0];
          acc[mi][ni][1] += rv1 * ct[mi][ni][1];
          acc[mi][ni][2] += rv2 * ct[mi][ni][2];
          acc[mi][ni][3] += rv3 * ct[mi][ni][3];
        }
      }
    }
  }
  #pragma unroll
  for (int mi=0; mi<4; ++mi){
    #pragma unroll
    for (int ni=0; ni<4; ++ni){
      #pragma unroll
      for (int rg=0; rg<4; ++rg){
        int t = t0 + rbase + mi*16 + (lane>>4)*4 + rg;
        int h = h0 + cbase + ni*16 + (lane&15);
        atomicAdd(&r_ol[(size_t)t*512 + h], acc[mi][ni][rg]);
      }
    }
  }
}

extern "C" void kernel_launch(void* const* d_in, const int* in_sizes, int n_in,
                              void* d_out, int out_size, void* d_ws, size_t ws_size,
                              hipStream_t stream) {
  const float* r    = (const float*)d_in[0];   // [1024][512]
  const float* W1   = (const float*)d_in[1];   // [512][512]
  const float* b1   = (const float*)d_in[2];   // [512]
  const float* W2   = (const float*)d_in[3];   // [262144][512]
  const float* b2   = (const float*)d_in[4];   // [262144] == [512 h][512 n]
  const float* Wout = (const float*)d_in[5];   // [32000][512]
  const float* bout = (const float*)d_in[6];   // [32000]
  float* logits = (float*)d_out;               // [1024][32000]

  float* x_f32 = (float*)d_ws;                            // 2 MiB
  float* r_ol  = (float*)((char*)d_ws + 1024*512*4);      // 2 MiB

  // x = relu(r @ W1^T + b1)
  gemm_plain<0><<<16, 512, 0, stream>>>(r, W1, b1, x_f32, 512);
  // r_ol = r @ b2_2d^T   (bias part of the einsum), initializes the atomic target
  gemm_plain<1><<<16, 512, 0, stream>>>(r, b2, nullptr, r_ol, 512);
  // r_ol += fused per-n big GEMM
  k2_fused<<<512, 512, 0, stream>>>(x_f32, r, W2, r_ol);
  // logits = r_ol @ W_out^T + b_out
  gemm_plain<2><<<1000, 512, 0, stream>>>(r_ol, Wout, bout, logits, 32000);
}